// Round 4
// baseline (63.361 us; speedup 1.0000x reference)
//
#include <hip/hip_runtime.h>
#include <hip/hip_bf16.h>

typedef __attribute__((ext_vector_type(8))) short bf16x8;
typedef __attribute__((ext_vector_type(4))) float f32x4;
typedef __attribute__((ext_vector_type(2))) float f32x2;
typedef unsigned int uint32;
typedef unsigned short ushort_t;
typedef __attribute__((ext_vector_type(4))) uint32 u32x4;

__device__ __forceinline__ ushort_t f2bf(float f) {
    unsigned int u = __float_as_uint(f);
    u = (u + 0x7FFFu + ((u >> 16) & 1u)) >> 16;
    return (ushort_t)u;
}

__device__ __forceinline__ uint32 cvt_pk_bf16(float lo, float hi) {
    uint32 r;
    asm("v_cvt_pk_bf16_f32 %0, %1, %2" : "=v"(r) : "v"(lo), "v"(hi));
    return r;
}

// Fused prep: blocks 0..4095 transpose x (NCHW fp32 -> NHWC bf16, batch<->XCD),
// blocks 4096..4671 repack weight fragment-major.
__global__ __launch_bounds__(256) void prep_all(const float* __restrict__ x,
                                                const float* __restrict__ w,
                                                ushort_t* __restrict__ xt,
                                                ushort_t* __restrict__ wT2) {
    int bi = blockIdx.x;
    int t = threadIdx.x;
    if (bi >= 4096) {
        // wT2[((tap*4+ks)*4+lu)*128 + f][j], c = ks*32+lu*8+j
        int idx = (bi - 4096) * 256 + t;   // 0..147455
        int tap = idx >> 14;
        int rem = idx & 16383;
        int j = rem & 7, f = (rem >> 3) & 127, lu = (rem >> 10) & 3, ks = rem >> 12;
        int c = ks * 32 + lu * 8 + j;
        wT2[idx] = f2bf(w[((size_t)f * 128 + c) * 9 + tap]);
        return;
    }
    __shared__ float tile[32][33];
    int b = bi & 7;
    int r2 = bi >> 3;
    int wb = r2 & 1, cb = (r2 >> 1) & 3, y = r2 >> 3;
    int lw = t & 31, lc = t >> 5;
    #pragma unroll
    for (int pass = 0; pass < 4; ++pass) {
        int c = cb * 32 + lc + pass * 8;
        tile[lc + pass * 8][lw] = x[(((size_t)b * 128 + c) * 64 + y) * 64 + wb * 32 + lw];
    }
    __syncthreads();
    int cc = t & 31, xl = t >> 5;
    #pragma unroll
    for (int pass = 0; pass < 4; ++pass) {
        int xll = xl + pass * 8;
        xt[(((size_t)b * 64 + y) * 64 + wb * 32 + xll) * 128 + cb * 32 + cc] =
            f2bf(tile[cc][xll]);
    }
}

__device__ __forceinline__ bf16x8 interp_chunk(u32x4 c0, u32x4 c1, u32x4 c2, u32x4 c3,
                                               f32x4 wv) {
    uint32 rr[4];
    #pragma unroll
    for (int i = 0; i < 4; ++i) {
        f32x2 a, s;
        uint32 u = c0[i];
        a.x = __uint_as_float(u << 16); a.y = __uint_as_float(u & 0xffff0000u);
        s = a * wv.x;
        u = c1[i];
        a.x = __uint_as_float(u << 16); a.y = __uint_as_float(u & 0xffff0000u);
        s += a * wv.y;
        u = c2[i];
        a.x = __uint_as_float(u << 16); a.y = __uint_as_float(u & 0xffff0000u);
        s += a * wv.z;
        u = c3[i];
        a.x = __uint_as_float(u << 16); a.y = __uint_as_float(u & 0xffff0000u);
        s += a * wv.w;
        rr[i] = cvt_pk_bf16(s.x, s.y);
    }
    u32x4 q = {rr[0], rr[1], rr[2], rr[3]};
    return __builtin_bit_cast(bf16x8, q);
}

__device__ __forceinline__ void mfma8(f32x4 (&acc)[8], const bf16x8 (&a)[8], bf16x8 bb) {
    #pragma unroll
    for (int ft = 0; ft < 8; ++ft)
        acc[ft] = __builtin_amdgcn_mfma_f32_16x16x32_bf16(a[ft], bb, acc[ft], 0, 0, 0);
}

// One tap's contribution for NKS K-steps starting at ksbase.
template<int NKS>
__device__ __forceinline__ void do_tap(const char* xb, const ushort_t* wT2,
                                       int o00, int o01, int o10, int o11,
                                       f32x4 wv, int co, int lu, int p,
                                       int k, int ksbase, f32x4 (&acc)[8]) {
    const int cbyte = ksbase * 64;
    u32x4 ga[4][2];
    #pragma unroll
    for (int h = 0; h < 2; ++h) {
        int off = cbyte + h * 64 + co;
        ga[0][h] = *(const u32x4*)(xb + o00 + off);
        ga[1][h] = *(const u32x4*)(xb + o01 + off);
        ga[2][h] = *(const u32x4*)(xb + o10 + off);
        ga[3][h] = *(const u32x4*)(xb + o11 + off);
    }
    const ushort_t* ab = wT2 + ((((size_t)k * 4 + ksbase) * 4 + lu) * 128 + p) * 8;
    bf16x8 a0[8];
    #pragma unroll
    for (int ft = 0; ft < 8; ++ft) a0[ft] = *(const bf16x8*)(ab + ft * 128);
    __builtin_amdgcn_sched_barrier(0);  // keep the batches issued up-front

    bf16x8 b0 = interp_chunk(ga[0][0], ga[1][0], ga[2][0], ga[3][0], wv);
    bf16x8 b1 = interp_chunk(ga[0][1], ga[1][1], ga[2][1], ga[3][1], wv);

    if constexpr (NKS == 4) {
        u32x4 gb[4][2];
        #pragma unroll
        for (int h = 0; h < 2; ++h) {
            int off = 128 + h * 64 + co;
            gb[0][h] = *(const u32x4*)(xb + o00 + off);
            gb[1][h] = *(const u32x4*)(xb + o01 + off);
            gb[2][h] = *(const u32x4*)(xb + o10 + off);
            gb[3][h] = *(const u32x4*)(xb + o11 + off);
        }
        __builtin_amdgcn_sched_barrier(0);
        mfma8(acc, a0, b0);
        bf16x8 a1[8];
        #pragma unroll
        for (int ft = 0; ft < 8; ++ft) a1[ft] = *(const bf16x8*)(ab + 4096 + ft * 128);
        bf16x8 b2 = interp_chunk(gb[0][0], gb[1][0], gb[2][0], gb[3][0], wv);
        bf16x8 b3 = interp_chunk(gb[0][1], gb[1][1], gb[2][1], gb[3][1], wv);
        bf16x8 a2[8];
        #pragma unroll
        for (int ft = 0; ft < 8; ++ft) a2[ft] = *(const bf16x8*)(ab + 8192 + ft * 128);
        mfma8(acc, a1, b1);
        bf16x8 a3[8];
        #pragma unroll
        for (int ft = 0; ft < 8; ++ft) a3[ft] = *(const bf16x8*)(ab + 12288 + ft * 128);
        mfma8(acc, a2, b2);
        mfma8(acc, a3, b3);
    } else {
        bf16x8 a1[8];
        #pragma unroll
        for (int ft = 0; ft < 8; ++ft) a1[ft] = *(const bf16x8*)(ab + 4096 + ft * 128);
        mfma8(acc, a0, b0);
        mfma8(acc, a1, b1);
    }
}

// Block = 256 thr = 4 waves = {2 pixel strips} x {2 tap groups}, tile 32pix x 128F.
// No main-loop barriers; waves run their 4.5 taps independently; 2-way K-split
// reduced through LDS at the end. Grid 1024 blocks = exactly 4/CU resident.
__global__ __launch_bounds__(256, 4) void dcn_main(
    const float* __restrict__ offset, const float* __restrict__ mask,
    const ushort_t* __restrict__ xt, const ushort_t* __restrict__ wT2,
    float* __restrict__ out)
{
    __shared__ float  pws_l[9][32][4];   // corner weights*mask*valid
    __shared__ uint32 pos_l[9][32];      // packed (y0*64+x0) | (y1*64+x1)<<16
    __shared__ float  red[2][128][17];   // K-split partials [strip][f][p]

    int bi = blockIdx.x;
    int b = bi & 7;                      // batch <-> XCD
    int rem = bi >> 3;
    int ho = rem >> 1, half = rem & 1;
    int wo0 = half * 32;
    int t = threadIdx.x, lane = t & 63, wid = t >> 6;
    int strip = wid & 1, tg = wid >> 1;
    int p = lane & 15, lu = lane >> 4;
    int pix = strip * 16 + p;
    int co = lu * 16;

    // ---- prologue: sampling params, 9 taps x 32 pixels ----
    for (int item = t; item < 288; item += 256) {
        int k = item >> 5, pi = item & 31;
        int wo = wo0 + pi;
        int ki = k / 3, kj = k - ki * 3;
        float dy = offset[(((size_t)b * 18 + 2 * k)     * 64 + ho) * 64 + wo];
        float dx = offset[(((size_t)b * 18 + 2 * k + 1) * 64 + ho) * 64 + wo];
        float m  = mask  [(((size_t)b * 9  + k)         * 64 + ho) * 64 + wo];
        float py = (float)(ho - 1 + ki) + dy;
        float px = (float)(wo - 1 + kj) + dx;
        float y0f = floorf(py), x0f = floorf(px);
        float ly = py - y0f, lx = px - x0f;
        float hy = 1.f - ly, hx = 1.f - lx;
        int y0 = (int)y0f, x0 = (int)x0f;
        int y1 = y0 + 1, x1 = x0 + 1;
        float vy0 = (y0 >= 0 && y0 < 64) ? 1.f : 0.f;
        float vy1 = (y1 >= 0 && y1 < 64) ? 1.f : 0.f;
        float vx0 = (x0 >= 0 && x0 < 64) ? 1.f : 0.f;
        float vx1 = (x1 >= 0 && x1 < 64) ? 1.f : 0.f;
        pws_l[k][pi][0] = hy * hx * m * vy0 * vx0;
        pws_l[k][pi][1] = hy * lx * m * vy0 * vx1;
        pws_l[k][pi][2] = ly * hx * m * vy1 * vx0;
        pws_l[k][pi][3] = ly * lx * m * vy1 * vx1;
        int y0c = min(max(y0, 0), 63), y1c = min(max(y1, 0), 63);
        int x0c = min(max(x0, 0), 63), x1c = min(max(x1, 0), 63);
        pos_l[k][pi] = (uint32)(y0c * 64 + x0c) | ((uint32)(y1c * 64 + x1c) << 16);
    }
    __syncthreads();

    const char* xb = (const char*)xt + (size_t)b * (64 * 64 * 256);
    f32x4 acc[8];
    #pragma unroll
    for (int i = 0; i < 8; ++i) acc[i] = (f32x4){0.f, 0.f, 0.f, 0.f};

    int kf = tg * 5;  // tg0: taps 0..3, tg1: taps 5..8; tap 4 split by channel
    #pragma unroll 1
    for (int i = 0; i < 4; ++i) {
        int k = kf + i;
        uint32 pp = pos_l[k][pix];
        f32x4 wv = *(const f32x4*)pws_l[k][pix];
        int i00 = pp & 0xffffu, i11 = pp >> 16;
        int o00 = i00 << 8, o11 = i11 << 8;
        int o01 = ((i00 & 0xffc0) | (i11 & 63)) << 8;
        int o10 = ((i11 & 0xffc0) | (i00 & 63)) << 8;
        do_tap<4>(xb, wT2, o00, o01, o10, o11, wv, co, lu, p, k, 0, acc);
    }
    {
        uint32 pp = pos_l[4][pix];
        f32x4 wv = *(const f32x4*)pws_l[4][pix];
        int i00 = pp & 0xffffu, i11 = pp >> 16;
        int o00 = i00 << 8, o11 = i11 << 8;
        int o01 = ((i00 & 0xffc0) | (i11 & 63)) << 8;
        int o10 = ((i11 & 0xffc0) | (i00 & 63)) << 8;
        do_tap<2>(xb, wT2, o00, o01, o10, o11, wv, co, lu, p, 4, tg * 2, acc);
    }

    // ---- epilogue: 2-way K-split reduce via LDS, tg0 stores ----
    if (tg == 1) {
        #pragma unroll
        for (int ft = 0; ft < 8; ++ft)
            #pragma unroll
            for (int r = 0; r < 4; ++r)
                red[strip][ft * 16 + lu * 4 + r][p] = acc[ft][r];
    }
    __syncthreads();
    if (tg == 0) {
        float* outb = out + (size_t)b * 128 * 4096 + ho * 64 + wo0 + strip * 16 + p;
        #pragma unroll
        for (int ft = 0; ft < 8; ++ft)
            #pragma unroll
            for (int r = 0; r < 4; ++r) {
                int f = ft * 16 + lu * 4 + r;
                outb[(size_t)f * 4096] = acc[ft][r] + red[strip][f][p];
            }
    }
}

extern "C" void kernel_launch(void* const* d_in, const int* in_sizes, int n_in,
                              void* d_out, int out_size, void* d_ws, size_t ws_size,
                              hipStream_t stream) {
    const float* x      = (const float*)d_in[0];
    const float* offset = (const float*)d_in[1];
    const float* mask   = (const float*)d_in[2];
    const float* weight = (const float*)d_in[3];
    float* out = (float*)d_out;

    ushort_t* xt  = (ushort_t*)d_ws;                       // 8 MiB
    ushort_t* wT2 = xt + (size_t)8 * 64 * 64 * 128;        // 288 KiB
    if (ws_size < (size_t)(8 * 64 * 64 * 128 + 9 * 16384) * 2) return;

    prep_all<<<4672, 256, 0, stream>>>(x, weight, xt, wT2);
    dcn_main<<<1024, 256, 0, stream>>>(offset, mask, xt, wT2, out);
}

// Round 5
// 50.501 us; speedup vs baseline: 1.2546x; 1.2546x over previous
//
#include <hip/hip_runtime.h>
#include <hip/hip_bf16.h>

typedef __attribute__((ext_vector_type(8))) short bf16x8;
typedef __attribute__((ext_vector_type(4))) float f32x4;
typedef __attribute__((ext_vector_type(2))) float f32x2;
typedef unsigned int uint32;
typedef unsigned short ushort_t;
typedef __attribute__((ext_vector_type(4))) uint32 u32x4;

#define SB0() __builtin_amdgcn_sched_barrier(0)
#define VMCNT(N) do { asm volatile("s_waitcnt vmcnt(" #N ")" ::: "memory"); SB0(); } while (0)

__device__ __forceinline__ ushort_t f2bf(float f) {
    unsigned int u = __float_as_uint(f);
    u = (u + 0x7FFFu + ((u >> 16) & 1u)) >> 16;
    return (ushort_t)u;
}

__device__ __forceinline__ uint32 cvt_pk_bf16(float lo, float hi) {
    uint32 r;
    asm("v_cvt_pk_bf16_f32 %0, %1, %2" : "=v"(r) : "v"(lo), "v"(hi));
    return r;
}

// asm gather: forced-issue 16B global load; completion via explicit VMCNT only.
template<int IMM>
__device__ __forceinline__ u32x4 gload(const char* p) {
    u32x4 r;
    asm volatile("global_load_dwordx4 %0, %1, off offset:%2"
                 : "=v"(r) : "v"(p), "n"(IMM));
    return r;
}

__device__ __forceinline__ void gload_lds16(const void* g, void* l) {
    __builtin_amdgcn_global_load_lds(
        (const __attribute__((address_space(1))) uint32*)g,
        (__attribute__((address_space(3))) uint32*)l, 16, 0, 0);
}

// Fused prep: blocks 0..4095 transpose x (NCHW fp32 -> NHWC bf16, batch<->XCD),
// blocks 4096..4671 repack weight fragment-major:
// elem (tap, f=ft*16+p, c=ks*32+lu*8+j) -> (((tap*4+ks)*8+ft)*64 + lu*16 + p)*8 + j
__global__ __launch_bounds__(256) void prep_all(const float* __restrict__ x,
                                                const float* __restrict__ w,
                                                ushort_t* __restrict__ xt,
                                                ushort_t* __restrict__ wT2) {
    int bi = blockIdx.x;
    int t = threadIdx.x;
    if (bi >= 4096) {
        int idx = (bi - 4096) * 256 + t;   // 0..147455
        int j  = idx & 7;
        int p  = (idx >> 3) & 15;
        int lu = (idx >> 7) & 3;
        int ft = (idx >> 9) & 7;
        int ks = (idx >> 12) & 3;
        int tap = idx >> 14;
        int f = ft * 16 + p;
        int c = ks * 32 + lu * 8 + j;
        wT2[idx] = f2bf(w[((size_t)f * 128 + c) * 9 + tap]);
        return;
    }
    __shared__ float tile[32][33];
    int b = bi & 7;
    int r2 = bi >> 3;
    int wb = r2 & 1, cb = (r2 >> 1) & 3, y = r2 >> 3;
    int lw = t & 31, lc = t >> 5;
    #pragma unroll
    for (int pass = 0; pass < 4; ++pass) {
        int c = cb * 32 + lc + pass * 8;
        tile[lc + pass * 8][lw] = x[(((size_t)b * 128 + c) * 64 + y) * 64 + wb * 32 + lw];
    }
    __syncthreads();
    int cc = t & 31, xl = t >> 5;
    #pragma unroll
    for (int pass = 0; pass < 4; ++pass) {
        int xll = xl + pass * 8;
        xt[(((size_t)b * 64 + y) * 64 + wb * 32 + xll) * 128 + cb * 32 + cc] =
            f2bf(tile[cc][xll]);
    }
}

__device__ __forceinline__ bf16x8 interp4(u32x4 c0, u32x4 c1, u32x4 c2, u32x4 c3,
                                          f32x4 wv) {
    uint32 rr[4];
    #pragma unroll
    for (int i = 0; i < 4; ++i) {
        f32x2 a, s;
        uint32 u = c0[i];
        a.x = __uint_as_float(u << 16); a.y = __uint_as_float(u & 0xffff0000u);
        s = a * wv.x;
        u = c1[i];
        a.x = __uint_as_float(u << 16); a.y = __uint_as_float(u & 0xffff0000u);
        s += a * wv.y;
        u = c2[i];
        a.x = __uint_as_float(u << 16); a.y = __uint_as_float(u & 0xffff0000u);
        s += a * wv.z;
        u = c3[i];
        a.x = __uint_as_float(u << 16); a.y = __uint_as_float(u & 0xffff0000u);
        s += a * wv.w;
        rr[i] = cvt_pk_bf16(s.x, s.y);
    }
    u32x4 q = {rr[0], rr[1], rr[2], rr[3]};
    return __builtin_bit_cast(bf16x8, q);
}

// Block = 256 thr = 4 waves, one (b,ho) output row; wave = 16 pix x 128F, full K.
// Gathers: asm loads + counted vmcnt, 1 K-step prefetch depth.
// A: LDS-staged per tap (dbuf) via global_load_lds; raw s_barrier (no drain).
__global__ __launch_bounds__(256, 2) void dcn_main(
    const float* __restrict__ offset, const float* __restrict__ mask,
    const ushort_t* __restrict__ xt, const ushort_t* __restrict__ wT2,
    float* __restrict__ out)
{
    __shared__ ushort_t Abuf[2][16384];   // 64 KB, A tile dbuf
    __shared__ float  pws_l[9][64][4];    // corner weights*mask*valid
    __shared__ uint32 pos_l[9][64];       // packed (y0*64+x0) | (y1*64+x1)<<16

    int bi = blockIdx.x;
    int b = bi & 7, ho = bi >> 3;         // batch <-> XCD
    int t = threadIdx.x, lane = t & 63, wid = t >> 6;
    int p = lane & 15, lu = lane >> 4;
    int pix = wid * 16 + p;

    // ---- prologue: stage tap 0 into buf0 (async), compute sampling params ----
    {
        const ushort_t* s0 = wT2 + t * 8;
        #pragma unroll
        for (int r = 0; r < 8; ++r)
            gload_lds16(s0 + r * 2048, &Abuf[0][(r * 256 + t) * 8]);
    }
    for (int item = t; item < 576; item += 256) {
        int k = item >> 6, pi = item & 63;
        int ki = k / 3, kj = k - ki * 3;
        float dy = offset[(((size_t)b * 18 + 2 * k)     * 64 + ho) * 64 + pi];
        float dx = offset[(((size_t)b * 18 + 2 * k + 1) * 64 + ho) * 64 + pi];
        float m  = mask  [(((size_t)b * 9  + k)         * 64 + ho) * 64 + pi];
        float py = (float)(ho - 1 + ki) + dy;
        float px = (float)(pi - 1 + kj) + dx;
        float y0f = floorf(py), x0f = floorf(px);
        float ly = py - y0f, lx = px - x0f;
        float hy = 1.f - ly, hx = 1.f - lx;
        int y0 = (int)y0f, x0 = (int)x0f;
        int y1 = y0 + 1, x1 = x0 + 1;
        float vy0 = (y0 >= 0 && y0 < 64) ? 1.f : 0.f;
        float vy1 = (y1 >= 0 && y1 < 64) ? 1.f : 0.f;
        float vx0 = (x0 >= 0 && x0 < 64) ? 1.f : 0.f;
        float vx1 = (x1 >= 0 && x1 < 64) ? 1.f : 0.f;
        pws_l[k][pi][0] = hy * hx * m * vy0 * vx0;
        pws_l[k][pi][1] = hy * lx * m * vy0 * vx1;
        pws_l[k][pi][2] = ly * hx * m * vy1 * vx0;
        pws_l[k][pi][3] = ly * lx * m * vy1 * vx1;
        int y0c = min(max(y0, 0), 63), y1c = min(max(y1, 0), 63);
        int x0c = min(max(x0, 0), 63), x1c = min(max(x1, 0), 63);
        pos_l[k][pi] = (uint32)(y0c * 64 + x0c) | ((uint32)(y1c * 64 + x1c) << 16);
    }
    asm volatile("s_waitcnt vmcnt(0)" ::: "memory");
    __syncthreads();   // prologue barrier (full drain OK, happens once)

    const char* xb = (const char*)xt + (size_t)b * (64 * 64 * 256);
    f32x4 acc[8];
    #pragma unroll
    for (int i = 0; i < 8; ++i) acc[i] = (f32x4){0.f, 0.f, 0.f, 0.f};

    const char *p00, *p01, *p10, *p11;
    f32x4 wv;
    auto tap_params = [&](int k, const char*& q00, const char*& q01,
                          const char*& q10, const char*& q11, f32x4& w4) {
        uint32 pp = pos_l[k][pix];
        w4 = *(const f32x4*)pws_l[k][pix];
        int i00 = pp & 0xffffu, i11 = pp >> 16;
        int o00 = i00 << 8, o11 = i11 << 8;
        int o01 = ((i00 & 0xffc0u) | (i11 & 63u)) << 8;
        int o10 = ((i11 & 0xffc0u) | (i00 & 63u)) << 8;
        int cl = lu * 16;
        q00 = xb + o00 + cl; q01 = xb + o01 + cl;
        q10 = xb + o10 + cl; q11 = xb + o11 + cl;
    };

    tap_params(0, p00, p01, p10, p11, wv);
    u32x4 g0 = gload<0>(p00), g1 = gload<0>(p01), g2 = gload<0>(p10), g3 = gload<0>(p11);
    SB0();

    #define MFMA_KS(KS, BF, AB)                                                  \
        do {                                                                     \
            _Pragma("unroll")                                                    \
            for (int ft = 0; ft < 8; ++ft) {                                     \
                bf16x8 aa = *(const bf16x8*)&(AB)[(((KS) * 8 + ft) * 64 + lane) * 8]; \
                acc[ft] = __builtin_amdgcn_mfma_f32_16x16x32_bf16(aa, (BF), acc[ft], 0, 0, 0); \
            }                                                                    \
        } while (0)

    #pragma unroll 1
    for (int tap = 0; tap < 8; ++tap) {
        const ushort_t* Ab = &Abuf[tap & 1][0];
        ushort_t* An = &Abuf[(tap + 1) & 1][0];
        // ks0: issue gath(ks1) + stage(tap+1); wait gath(ks0)
        u32x4 h0 = gload<64>(p00), h1 = gload<64>(p01), h2 = gload<64>(p10), h3 = gload<64>(p11);
        {
            const ushort_t* ss = wT2 + (size_t)(tap + 1) * 16384 + t * 8;
            #pragma unroll
            for (int r = 0; r < 8; ++r)
                gload_lds16(ss + r * 2048, &An[(r * 256 + t) * 8]);
        }
        SB0();
        VMCNT(12);
        {
            bf16x8 bf = interp4(g0, g1, g2, g3, wv);
            MFMA_KS(0, bf, Ab);
        }
        // ks1
        u32x4 i0 = gload<128>(p00), i1 = gload<128>(p01), i2 = gload<128>(p10), i3 = gload<128>(p11);
        SB0();
        VMCNT(12);
        {
            bf16x8 bf = interp4(h0, h1, h2, h3, wv);
            MFMA_KS(1, bf, Ab);
        }
        // ks2: wait drains stage + gath(ks2)
        u32x4 j0 = gload<192>(p00), j1 = gload<192>(p01), j2 = gload<192>(p10), j3 = gload<192>(p11);
        SB0();
        VMCNT(4);
        {
            bf16x8 bf = interp4(i0, i1, i2, i3, wv);
            MFMA_KS(2, bf, Ab);
        }
        // ks3: prefetch next tap's gath(ks0)
        const char *q00, *q01, *q10, *q11;
        f32x4 wv2;
        tap_params(tap + 1, q00, q01, q10, q11, wv2);
        g0 = gload<0>(q00); g1 = gload<0>(q01); g2 = gload<0>(q10); g3 = gload<0>(q11);
        SB0();
        VMCNT(4);
        {
            bf16x8 bf = interp4(j0, j1, j2, j3, wv);
            MFMA_KS(3, bf, Ab);
        }
        p00 = q00; p01 = q01; p10 = q10; p11 = q11; wv = wv2;
        SB0();
        __builtin_amdgcn_s_barrier();   // raw: stage already drained, gath(next) stays in flight
        SB0();
    }

    // ---- tap 8 (no stage) ----
    {
        const ushort_t* Ab = &Abuf[0][0];
        u32x4 h0 = gload<64>(p00), h1 = gload<64>(p01), h2 = gload<64>(p10), h3 = gload<64>(p11);
        SB0();
        VMCNT(4);
        { bf16x8 bf = interp4(g0, g1, g2, g3, wv); MFMA_KS(0, bf, Ab); }
        u32x4 i0 = gload<128>(p00), i1 = gload<128>(p01), i2 = gload<128>(p10), i3 = gload<128>(p11);
        SB0();
        VMCNT(4);
        { bf16x8 bf = interp4(h0, h1, h2, h3, wv); MFMA_KS(1, bf, Ab); }
        u32x4 j0 = gload<192>(p00), j1 = gload<192>(p01), j2 = gload<192>(p10), j3 = gload<192>(p11);
        SB0();
        VMCNT(4);
        { bf16x8 bf = interp4(i0, i1, i2, i3, wv); MFMA_KS(2, bf, Ab); }
        VMCNT(0);
        { bf16x8 bf = interp4(j0, j1, j2, j3, wv); MFMA_KS(3, bf, Ab); }
    }

    // ---- epilogue: D col = pixel (lane&15), row = (lane>>4)*4 + r ----
    float* outb = out + (size_t)b * 128 * 4096 + ho * 64 + wid * 16 + p;
    #pragma unroll
    for (int ft = 0; ft < 8; ++ft)
        #pragma unroll
        for (int r = 0; r < 4; ++r) {
            int f = ft * 16 + lu * 4 + r;
            outb[(size_t)f * 4096] = acc[ft][r];
        }
    #undef MFMA_KS
}

extern "C" void kernel_launch(void* const* d_in, const int* in_sizes, int n_in,
                              void* d_out, int out_size, void* d_ws, size_t ws_size,
                              hipStream_t stream) {
    const float* x      = (const float*)d_in[0];
    const float* offset = (const float*)d_in[1];
    const float* mask   = (const float*)d_in[2];
    const float* weight = (const float*)d_in[3];
    float* out = (float*)d_out;

    ushort_t* xt  = (ushort_t*)d_ws;                       // 8 MiB
    ushort_t* wT2 = xt + (size_t)8 * 64 * 64 * 128;        // 288 KiB
    if (ws_size < (size_t)(8 * 64 * 64 * 128 + 9 * 16384) * 2) return;

    prep_all<<<4672, 256, 0, stream>>>(x, weight, xt, wT2);
    dcn_main<<<512, 256, 0, stream>>>(offset, mask, xt, wT2, out);
}